// Round 3
// baseline (223.901 us; speedup 1.0000x reference)
//
#include <hip/hip_runtime.h>
#include <hip/hip_bf16.h>

#define M_DIM 32768
#define K_DIM 1024
#define N_POOL 1024

#define BM 256
#define BN 256
#define BK 64
#define KTILES (K_DIM / BK)   // 16

typedef __attribute__((ext_vector_type(8))) short bf16x8;
typedef __attribute__((ext_vector_type(4))) float f32x4;

typedef __attribute__((address_space(3))) unsigned int lds_uint;
typedef const __attribute__((address_space(1))) unsigned int g_uint;

__device__ __forceinline__ unsigned short f2bf(float f) {
    unsigned int u = __builtin_bit_cast(unsigned int, f);
    unsigned int lsb = (u >> 16) & 1u;
    u += 0x7fffu + lsb;
    return (unsigned short)(u >> 16);
}

__device__ __forceinline__ unsigned int f2bf2(float lo, float hi) {
    // packed RNE cvt — compiler emits v_cvt_pk_bf16_f32
    __hip_bfloat162 h2 = __float22bfloat162_rn(make_float2(lo, hi));
    union { __hip_bfloat162 h; unsigned int u; } c;
    c.h = h2;
    return c.u;
}

// ---------------- prep: fold avgpool(k=4) into weight/bias, cast to bf16 ----
__global__ __launch_bounds__(256) void prep_kernel(
        const float* __restrict__ W, const float* __restrict__ b,
        unsigned short* __restrict__ wp, float* __restrict__ bp) {
    int n = blockIdx.x;
    int t = threadIdx.x;
    const float4* r0 = (const float4*)(W + (size_t)(4 * n + 0) * K_DIM);
    const float4* r1 = (const float4*)(W + (size_t)(4 * n + 1) * K_DIM);
    const float4* r2 = (const float4*)(W + (size_t)(4 * n + 2) * K_DIM);
    const float4* r3 = (const float4*)(W + (size_t)(4 * n + 3) * K_DIM);
    float4 a0 = r0[t], a1 = r1[t], a2 = r2[t], a3 = r3[t];
    float sx = (a0.x + a1.x + a2.x + a3.x) * 0.25f;
    float sy = (a0.y + a1.y + a2.y + a3.y) * 0.25f;
    float sz = (a0.z + a1.z + a2.z + a3.z) * 0.25f;
    float sw = (a0.w + a1.w + a2.w + a3.w) * 0.25f;
    ushort4 h;
    h.x = f2bf(sx); h.y = f2bf(sy); h.z = f2bf(sz); h.w = f2bf(sw);
    *(ushort4*)&wp[(size_t)n * K_DIM + t * 4] = h;
    if (t == 0)
        bp[n] = 0.25f * (b[4 * n] + b[4 * n + 1] + b[4 * n + 2] + b[4 * n + 3]);
}

// ======================= 256x256 4-phase GEMM =======================
// LDS: [r][BK] bf16 rows (128 B), 16B chunk col swizzled: slot = c16 ^ (r&7).
// A: reg-staged (f32 -> cvt_pk -> swizzled ds_write). B: global_load_lds with
// pre-swizzled global source (linear LDS dest), same involution.

__device__ __forceinline__ bf16x8 ldfrag(const unsigned short* base, int r, int c16) {
    return *(const bf16x8*)&base[r * 64 + (((c16) ^ (r & 7)) << 3)];
}

struct AStage { float4 av[8]; };

__device__ __forceinline__ void a_issue(AStage& s, const float4* __restrict__ xg,
                                        int m0, int kc, int tid) {
#pragma unroll
    for (int j = 0; j < 4; ++j) {
        int p = j * 512 + tid;            // 16B-out-chunk index within tile
        int row = p >> 3, c16 = p & 7;
        size_t base = (size_t)(m0 + row) * 256 + (kc >> 2) + c16 * 2;
        s.av[2 * j]     = xg[base];
        s.av[2 * j + 1] = xg[base + 1];
    }
}

__device__ __forceinline__ void a_write(const AStage& s, unsigned short* An, int tid) {
#pragma unroll
    for (int j = 0; j < 4; ++j) {
        int p = j * 512 + tid;
        int row = p >> 3, c16 = p & 7;
        union { bf16x8 v; unsigned int u[4]; } pk;
        pk.u[0] = f2bf2(s.av[2 * j].x,     s.av[2 * j].y);
        pk.u[1] = f2bf2(s.av[2 * j].z,     s.av[2 * j].w);
        pk.u[2] = f2bf2(s.av[2 * j + 1].x, s.av[2 * j + 1].y);
        pk.u[3] = f2bf2(s.av[2 * j + 1].z, s.av[2 * j + 1].w);
        *(bf16x8*)&An[row * 64 + ((c16 ^ (row & 7)) << 3)] = pk.v;
    }
}

__device__ __forceinline__ void b_issue(const unsigned short* __restrict__ wp,
                                        unsigned short* Bn, int n0, int kc,
                                        int wid, int lane) {
#pragma unroll
    for (int i = 0; i < 4; ++i) {
        int row0 = (wid * 4 + i) * 8;
        int n = n0 + row0 + (lane >> 3);
        int g = (lane & 7) ^ (lane >> 3);   // swizzled source chunk
        __builtin_amdgcn_global_load_lds(
            (g_uint*)(wp + (size_t)n * K_DIM + kc + g * 8),
            (lds_uint*)&Bn[row0 * 64], 16, 0, 0);
    }
}

__global__ __launch_bounds__(512, 2) void gemm_kernel(
        const float* __restrict__ x, const unsigned short* __restrict__ wp,
        const float* __restrict__ bp, float* __restrict__ partial) {
    __shared__ unsigned short As[2][BM * BK];   // 2 x 32 KB
    __shared__ unsigned short Bs[2][BN * BK];   // 2 x 32 KB

    // XCD-chunked swizzle (512 % 8 == 0 -> simple form is bijective)
    int bid = blockIdx.x;
    int wg = (bid & 7) * 64 + (bid >> 3);
    int nblk = wg & 3;               // n-inner: 4 n-tiles share an A-stripe per XCD
    int mblk = wg >> 2;
    int m0 = mblk * BM;
    int n0 = nblk * BN;

    int tid = threadIdx.x;
    int lane = tid & 63;
    int wid = tid >> 6;              // 0..7
    int wm = wid >> 2, wn = wid & 3; // 2 x 4 wave grid; wave tile 128x64
    int rl = lane & 15;
    int q = lane >> 4;               // 0..3

    f32x4 acc[8][4];
#pragma unroll
    for (int i = 0; i < 8; ++i)
#pragma unroll
        for (int j = 0; j < 4; ++j)
            acc[i][j] = (f32x4)(0.0f);

    const float4* xg = (const float4*)x;

    // ---- prologue: stage tile 0 into buf 0, full drain, barrier ----
    {
        AStage sa;
        a_issue(sa, xg, m0, 0, tid);
        b_issue(wp, Bs[0], n0, 0, wid, lane);
        a_write(sa, As[0], tid);
        asm volatile("s_waitcnt vmcnt(0) lgkmcnt(0)" ::: "memory");
        __builtin_amdgcn_sched_barrier(0);
        __builtin_amdgcn_s_barrier();
    }

#pragma unroll 1
    for (int kt = 0; kt < KTILES; ++kt) {
        const int cur = kt & 1;
        const bool stage = (kt + 1) < KTILES;
        const int kc = (kt + 1) * BK;
        const unsigned short* Ac = As[cur];
        const unsigned short* Bc = Bs[cur];
        unsigned short* An = As[cur ^ 1];
        unsigned short* Bn = Bs[cur ^ 1];

        bf16x8 af0[4][2], af1[4][2], bf0[2][2], bf1[2][2];
        AStage sa;

        // ---------------- P0: reads for Q00 + all stage issues ----------------
#pragma unroll
        for (int mi = 0; mi < 4; ++mi)
#pragma unroll
            for (int ks = 0; ks < 2; ++ks)
                af0[mi][ks] = ldfrag(Ac, wm * 128 + mi * 16 + rl, ks * 4 + q);
#pragma unroll
        for (int ni = 0; ni < 2; ++ni)
#pragma unroll
            for (int ks = 0; ks < 2; ++ks)
                bf0[ni][ks] = ldfrag(Bc, wn * 64 + ni * 16 + rl, ks * 4 + q);
        if (stage) {
            a_issue(sa, xg, m0, kc, tid);   // A first (oldest in vmcnt queue)
            b_issue(wp, Bn, n0, kc, wid, lane);
        }
        __builtin_amdgcn_s_barrier();
        __builtin_amdgcn_s_setprio(1);
#pragma unroll
        for (int ks = 0; ks < 2; ++ks)
#pragma unroll
            for (int mi = 0; mi < 4; ++mi)
#pragma unroll
                for (int ni = 0; ni < 2; ++ni)
                    acc[mi][ni] = __builtin_amdgcn_mfma_f32_16x16x32_bf16(
                        af0[mi][ks], bf0[ni][ks], acc[mi][ni], 0, 0, 0);
        __builtin_amdgcn_s_setprio(0);
        __builtin_amdgcn_s_barrier();

        // ---------------- P1: reads bf1, MFMA Q01 ----------------
#pragma unroll
        for (int ni = 0; ni < 2; ++ni)
#pragma unroll
            for (int ks = 0; ks < 2; ++ks)
                bf1[ni][ks] = ldfrag(Bc, wn * 64 + (ni + 2) * 16 + rl, ks * 4 + q);
        __builtin_amdgcn_s_barrier();
        __builtin_amdgcn_s_setprio(1);
#pragma unroll
        for (int ks = 0; ks < 2; ++ks)
#pragma unroll
            for (int mi = 0; mi < 4; ++mi)
#pragma unroll
                for (int ni = 0; ni < 2; ++ni)
                    acc[mi][ni + 2] = __builtin_amdgcn_mfma_f32_16x16x32_bf16(
                        af0[mi][ks], bf1[ni][ks], acc[mi][ni + 2], 0, 0, 0);
        __builtin_amdgcn_s_setprio(0);
        __builtin_amdgcn_s_barrier();

        // ---------------- P2: reads af1, A cvt+ds_write, MFMA Q11 ----------------
#pragma unroll
        for (int mi = 0; mi < 4; ++mi)
#pragma unroll
            for (int ks = 0; ks < 2; ++ks)
                af1[mi][ks] = ldfrag(Ac, wm * 128 + (mi + 4) * 16 + rl, ks * 4 + q);
        if (stage)
            a_write(sa, An, tid);   // compiler inserts counted vmcnt (B-glds younger)
        __builtin_amdgcn_s_barrier();
        __builtin_amdgcn_s_setprio(1);
#pragma unroll
        for (int ks = 0; ks < 2; ++ks)
#pragma unroll
            for (int mi = 0; mi < 4; ++mi)
#pragma unroll
                for (int ni = 0; ni < 2; ++ni)
                    acc[mi + 4][ni + 2] = __builtin_amdgcn_mfma_f32_16x16x32_bf16(
                        af1[mi][ks], bf1[ni][ks], acc[mi + 4][ni + 2], 0, 0, 0);
        __builtin_amdgcn_s_setprio(0);
        __builtin_amdgcn_s_barrier();

        // ---------------- P3: MFMA Q10, tile-boundary drain ----------------
        __builtin_amdgcn_s_setprio(1);
#pragma unroll
        for (int ks = 0; ks < 2; ++ks)
#pragma unroll
            for (int mi = 0; mi < 4; ++mi)
#pragma unroll
                for (int ni = 0; ni < 2; ++ni)
                    acc[mi + 4][ni] = __builtin_amdgcn_mfma_f32_16x16x32_bf16(
                        af1[mi][ks], bf0[ni][ks], acc[mi + 4][ni], 0, 0, 0);
        __builtin_amdgcn_s_setprio(0);
        // B-glds (issued P0, ~3 phases in flight) + A ds_writes must land
        asm volatile("s_waitcnt vmcnt(0) lgkmcnt(0)" ::: "memory");
        __builtin_amdgcn_sched_barrier(0);
        __builtin_amdgcn_s_barrier();
    }

    // ---- epilogue: bias + tanh-gelu*2 + row-max over wave's 64-col slice ----
    float bv[4];
#pragma unroll
    for (int ni = 0; ni < 4; ++ni)
        bv[ni] = bp[n0 + wn * 64 + ni * 16 + rl];

    const float GC = 0.7978845608028654f;
#pragma unroll
    for (int mi = 0; mi < 8; ++mi) {
#pragma unroll
        for (int j = 0; j < 4; ++j) {
            float mx = -3.4e38f;
#pragma unroll
            for (int ni = 0; ni < 4; ++ni) {
                float y = acc[mi][ni][j] + bv[ni];
                float z = GC * (y + 0.044715f * y * y * y);
                float e = __expf(2.0f * z);
                float th = 1.0f - 2.0f / (e + 1.0f);   // tanh(z)
                float g = y * (1.0f + th);             // 0.5*(1+tanh)*y*SCALE(2)
                mx = fmaxf(mx, g);
            }
#pragma unroll
            for (int s = 1; s < 16; s <<= 1)
                mx = fmaxf(mx, __shfl_xor(mx, s, 64));
            if (rl == 0) {
                int grow = m0 + wm * 128 + mi * 16 + q * 4 + j;
                partial[(size_t)(nblk * 4 + wn) * M_DIM + grow] = mx;
            }
        }
    }
}

// ---------------- final reduce: max over 16 column-chunks -------------------
__global__ __launch_bounds__(256) void reduce_kernel(
        const float* __restrict__ partial, float* __restrict__ out) {
    int m = blockIdx.x * 256 + threadIdx.x;
    float mx = -3.4e38f;
#pragma unroll
    for (int c = 0; c < 16; ++c)
        mx = fmaxf(mx, partial[(size_t)c * M_DIM + m]);
    out[m] = mx;
}

extern "C" void kernel_launch(void* const* d_in, const int* in_sizes, int n_in,
                              void* d_out, int out_size, void* d_ws, size_t ws_size,
                              hipStream_t stream) {
    const float* x = (const float*)d_in[0];
    const float* W = (const float*)d_in[1];
    const float* bias = (const float*)d_in[2];
    float* out = (float*)d_out;

    unsigned short* wp = (unsigned short*)d_ws;                         // 2 MB
    float* bp = (float*)((char*)d_ws + 2 * 1024 * 1024);                // 4 KB
    float* partial = (float*)((char*)d_ws + 2 * 1024 * 1024 + 4096);    // 2 MB

    prep_kernel<<<N_POOL, 256, 0, stream>>>(W, bias, wp, bp);
    gemm_kernel<<<(M_DIM / BM) * (N_POOL / BN), 512, 0, stream>>>(x, wp, bp, partial);
    reduce_kernel<<<M_DIM / 256, 256, 0, stream>>>(partial, out);
}

// Round 4
// 182.449 us; speedup vs baseline: 1.2272x; 1.2272x over previous
//
#include <hip/hip_runtime.h>
#include <hip/hip_bf16.h>

#define M_DIM 32768
#define K_DIM 1024
#define N_POOL 1024

#define BM 256
#define BN 256
#define BK 64
#define KTILES (K_DIM / BK)   // 16

typedef __attribute__((ext_vector_type(8))) short bf16x8;
typedef __attribute__((ext_vector_type(4))) float f32x4;

typedef __attribute__((address_space(3))) unsigned int lds_uint;
typedef const __attribute__((address_space(1))) unsigned int g_uint;

__device__ __forceinline__ unsigned short f2bf(float f) {
    unsigned int u = __builtin_bit_cast(unsigned int, f);
    unsigned int lsb = (u >> 16) & 1u;
    u += 0x7fffu + lsb;
    return (unsigned short)(u >> 16);
}

__device__ __forceinline__ unsigned int f2bf2(float lo, float hi) {
    // packed RNE cvt — compiler emits v_cvt_pk_bf16_f32
    __hip_bfloat162 h2 = __float22bfloat162_rn(make_float2(lo, hi));
    union { __hip_bfloat162 h; unsigned int u; } c;
    c.h = h2;
    return c.u;
}

// ---------------- prep: fold avgpool(k=4) into weight/bias, cast to bf16 ----
__global__ __launch_bounds__(256) void prep_kernel(
        const float* __restrict__ W, const float* __restrict__ b,
        unsigned short* __restrict__ wp, float* __restrict__ bp) {
    int n = blockIdx.x;
    int t = threadIdx.x;
    const float4* r0 = (const float4*)(W + (size_t)(4 * n + 0) * K_DIM);
    const float4* r1 = (const float4*)(W + (size_t)(4 * n + 1) * K_DIM);
    const float4* r2 = (const float4*)(W + (size_t)(4 * n + 2) * K_DIM);
    const float4* r3 = (const float4*)(W + (size_t)(4 * n + 3) * K_DIM);
    float4 a0 = r0[t], a1 = r1[t], a2 = r2[t], a3 = r3[t];
    float sx = (a0.x + a1.x + a2.x + a3.x) * 0.25f;
    float sy = (a0.y + a1.y + a2.y + a3.y) * 0.25f;
    float sz = (a0.z + a1.z + a2.z + a3.z) * 0.25f;
    float sw = (a0.w + a1.w + a2.w + a3.w) * 0.25f;
    ushort4 h;
    h.x = f2bf(sx); h.y = f2bf(sy); h.z = f2bf(sz); h.w = f2bf(sw);
    *(ushort4*)&wp[(size_t)n * K_DIM + t * 4] = h;
    if (t == 0)
        bp[n] = 0.25f * (b[4 * n] + b[4 * n + 1] + b[4 * n + 2] + b[4 * n + 3]);
}

// ======================= 256x256 4-phase GEMM =======================
// LDS: [r][BK] bf16 rows (128 B), 16B chunk col swizzled: slot = c16 ^ (r&7).
// A: reg-staged (f32 -> cvt_pk -> swizzled ds_write). B: global_load_lds with
// pre-swizzled global source (linear LDS dest), same involution.

__device__ __forceinline__ bf16x8 ldfrag(const unsigned short* base, int r, int c16) {
    return *(const bf16x8*)&base[r * 64 + (((c16) ^ (r & 7)) << 3)];
}

struct AStage { float4 av[8]; };

__device__ __forceinline__ void a_issue(AStage& s, const float4* __restrict__ xg,
                                        int m0, int kc, int tid) {
#pragma unroll
    for (int j = 0; j < 4; ++j) {
        int p = j * 512 + tid;            // 16B-out-chunk index within tile
        int row = p >> 3, c16 = p & 7;
        size_t base = (size_t)(m0 + row) * 256 + (kc >> 2) + c16 * 2;
        s.av[2 * j]     = xg[base];
        s.av[2 * j + 1] = xg[base + 1];
    }
}

__device__ __forceinline__ void a_write(const AStage& s, unsigned short* An, int tid) {
#pragma unroll
    for (int j = 0; j < 4; ++j) {
        int p = j * 512 + tid;
        int row = p >> 3, c16 = p & 7;
        union { bf16x8 v; unsigned int u[4]; } pk;
        pk.u[0] = f2bf2(s.av[2 * j].x,     s.av[2 * j].y);
        pk.u[1] = f2bf2(s.av[2 * j].z,     s.av[2 * j].w);
        pk.u[2] = f2bf2(s.av[2 * j + 1].x, s.av[2 * j + 1].y);
        pk.u[3] = f2bf2(s.av[2 * j + 1].z, s.av[2 * j + 1].w);
        *(bf16x8*)&An[row * 64 + ((c16 ^ (row & 7)) << 3)] = pk.v;
    }
}

__device__ __forceinline__ void b_issue(const unsigned short* __restrict__ wp,
                                        unsigned short* Bn, int n0, int kc,
                                        int wid, int lane) {
#pragma unroll
    for (int i = 0; i < 4; ++i) {
        int row0 = (wid * 4 + i) * 8;
        int n = n0 + row0 + (lane >> 3);
        int g = (lane & 7) ^ (lane >> 3);   // swizzled source chunk
        __builtin_amdgcn_global_load_lds(
            (g_uint*)(wp + (size_t)n * K_DIM + kc + g * 8),
            (lds_uint*)&Bn[row0 * 64], 16, 0, 0);
    }
}

__global__ __launch_bounds__(512, 1) void gemm_kernel(
        const float* __restrict__ x, const unsigned short* __restrict__ wp,
        const float* __restrict__ bp, float* __restrict__ partial) {
    __shared__ unsigned short As[2][BM * BK];   // 2 x 32 KB
    __shared__ unsigned short Bs[2][BN * BK];   // 2 x 32 KB

    // XCD-chunked swizzle (512 % 8 == 0 -> simple form is bijective)
    int bid = blockIdx.x;
    int wg = (bid & 7) * 64 + (bid >> 3);
    int nblk = wg & 3;               // n-inner: 4 n-tiles share an A-stripe per XCD
    int mblk = wg >> 2;
    int m0 = mblk * BM;
    int n0 = nblk * BN;

    int tid = threadIdx.x;
    int lane = tid & 63;
    int wid = tid >> 6;              // 0..7
    int wm = wid >> 2, wn = wid & 3; // 2 x 4 wave grid; wave tile 128x64
    int rl = lane & 15;
    int q = lane >> 4;               // 0..3

    f32x4 acc[8][4];
#pragma unroll
    for (int i = 0; i < 8; ++i)
#pragma unroll
        for (int j = 0; j < 4; ++j)
            acc[i][j] = (f32x4)(0.0f);

    const float4* xg = (const float4*)x;

    // ---- prologue: stage tile 0 into buf 0, full drain, barrier ----
    {
        AStage sa;
        a_issue(sa, xg, m0, 0, tid);
        b_issue(wp, Bs[0], n0, 0, wid, lane);
        a_write(sa, As[0], tid);
        asm volatile("s_waitcnt vmcnt(0) lgkmcnt(0)" ::: "memory");
        __builtin_amdgcn_sched_barrier(0);
        __builtin_amdgcn_s_barrier();
    }

#pragma unroll 1
    for (int kt = 0; kt < KTILES; ++kt) {
        const int cur = kt & 1;
        const bool stage = (kt + 1) < KTILES;
        const int kc = (kt + 1) * BK;
        const unsigned short* Ac = As[cur];
        const unsigned short* Bc = Bs[cur];
        unsigned short* An = As[cur ^ 1];
        unsigned short* Bn = Bs[cur ^ 1];

        bf16x8 af0[4][2], af1[4][2], bf0[2][2], bf1[2][2];
        AStage sa;

        // ---------------- P0: reads for Q00 + all stage issues ----------------
#pragma unroll
        for (int mi = 0; mi < 4; ++mi)
#pragma unroll
            for (int ks = 0; ks < 2; ++ks)
                af0[mi][ks] = ldfrag(Ac, wm * 128 + mi * 16 + rl, ks * 4 + q);
#pragma unroll
        for (int ni = 0; ni < 2; ++ni)
#pragma unroll
            for (int ks = 0; ks < 2; ++ks)
                bf0[ni][ks] = ldfrag(Bc, wn * 64 + ni * 16 + rl, ks * 4 + q);
        if (stage) {
            a_issue(sa, xg, m0, kc, tid);   // A first (oldest in vmcnt queue)
            b_issue(wp, Bn, n0, kc, wid, lane);
        }
        __builtin_amdgcn_s_barrier();
        __builtin_amdgcn_s_setprio(1);
#pragma unroll
        for (int ks = 0; ks < 2; ++ks)
#pragma unroll
            for (int mi = 0; mi < 4; ++mi)
#pragma unroll
                for (int ni = 0; ni < 2; ++ni)
                    acc[mi][ni] = __builtin_amdgcn_mfma_f32_16x16x32_bf16(
                        af0[mi][ks], bf0[ni][ks], acc[mi][ni], 0, 0, 0);
        __builtin_amdgcn_s_setprio(0);
        __builtin_amdgcn_s_barrier();

        // ---------------- P1: reads bf1, MFMA Q01 ----------------
#pragma unroll
        for (int ni = 0; ni < 2; ++ni)
#pragma unroll
            for (int ks = 0; ks < 2; ++ks)
                bf1[ni][ks] = ldfrag(Bc, wn * 64 + (ni + 2) * 16 + rl, ks * 4 + q);
        __builtin_amdgcn_s_barrier();
        __builtin_amdgcn_s_setprio(1);
#pragma unroll
        for (int ks = 0; ks < 2; ++ks)
#pragma unroll
            for (int mi = 0; mi < 4; ++mi)
#pragma unroll
                for (int ni = 0; ni < 2; ++ni)
                    acc[mi][ni + 2] = __builtin_amdgcn_mfma_f32_16x16x32_bf16(
                        af0[mi][ks], bf1[ni][ks], acc[mi][ni + 2], 0, 0, 0);
        __builtin_amdgcn_s_setprio(0);
        __builtin_amdgcn_s_barrier();

        // ---------------- P2: reads af1, A cvt+ds_write, MFMA Q11 ----------------
#pragma unroll
        for (int mi = 0; mi < 4; ++mi)
#pragma unroll
            for (int ks = 0; ks < 2; ++ks)
                af1[mi][ks] = ldfrag(Ac, wm * 128 + (mi + 4) * 16 + rl, ks * 4 + q);
        if (stage)
            a_write(sa, An, tid);   // compiler inserts counted vmcnt (B-glds younger)
        __builtin_amdgcn_s_barrier();
        __builtin_amdgcn_s_setprio(1);
#pragma unroll
        for (int ks = 0; ks < 2; ++ks)
#pragma unroll
            for (int mi = 0; mi < 4; ++mi)
#pragma unroll
                for (int ni = 0; ni < 2; ++ni)
                    acc[mi + 4][ni + 2] = __builtin_amdgcn_mfma_f32_16x16x32_bf16(
                        af1[mi][ks], bf1[ni][ks], acc[mi + 4][ni + 2], 0, 0, 0);
        __builtin_amdgcn_s_setprio(0);
        __builtin_amdgcn_s_barrier();

        // ---------------- P3: re-read bf0 (short live range), MFMA Q10, drain ----
        bf16x8 bf0b[2][2];
#pragma unroll
        for (int ni = 0; ni < 2; ++ni)
#pragma unroll
            for (int ks = 0; ks < 2; ++ks)
                bf0b[ni][ks] = ldfrag(Bc, wn * 64 + ni * 16 + rl, ks * 4 + q);
        __builtin_amdgcn_s_setprio(1);
#pragma unroll
        for (int ks = 0; ks < 2; ++ks)
#pragma unroll
            for (int mi = 0; mi < 4; ++mi)
#pragma unroll
                for (int ni = 0; ni < 2; ++ni)
                    acc[mi + 4][ni] = __builtin_amdgcn_mfma_f32_16x16x32_bf16(
                        af1[mi][ks], bf0b[ni][ks], acc[mi + 4][ni], 0, 0, 0);
        __builtin_amdgcn_s_setprio(0);
        // B-glds (issued P0, ~3 phases in flight) + A ds_writes must land
        asm volatile("s_waitcnt vmcnt(0) lgkmcnt(0)" ::: "memory");
        __builtin_amdgcn_sched_barrier(0);
        __builtin_amdgcn_s_barrier();
    }

    // ---- epilogue: bias + tanh-gelu*2 + row-max over wave's 64-col slice ----
    float bv[4];
#pragma unroll
    for (int ni = 0; ni < 4; ++ni)
        bv[ni] = bp[n0 + wn * 64 + ni * 16 + rl];

    const float GC = 0.7978845608028654f;
#pragma unroll
    for (int mi = 0; mi < 8; ++mi) {
#pragma unroll
        for (int j = 0; j < 4; ++j) {
            float mx = -3.4e38f;
#pragma unroll
            for (int ni = 0; ni < 4; ++ni) {
                float y = acc[mi][ni][j] + bv[ni];
                float z = GC * (y + 0.044715f * y * y * y);
                float e = __expf(2.0f * z);
                float th = 1.0f - 2.0f / (e + 1.0f);   // tanh(z)
                float g = y * (1.0f + th);             // 0.5*(1+tanh)*y*SCALE(2)
                mx = fmaxf(mx, g);
            }
#pragma unroll
            for (int s = 1; s < 16; s <<= 1)
                mx = fmaxf(mx, __shfl_xor(mx, s, 64));
            if (rl == 0) {
                int grow = m0 + wm * 128 + mi * 16 + q * 4 + j;
                partial[(size_t)(nblk * 4 + wn) * M_DIM + grow] = mx;
            }
        }
    }
}

// ---------------- final reduce: max over 16 column-chunks -------------------
__global__ __launch_bounds__(256) void reduce_kernel(
        const float* __restrict__ partial, float* __restrict__ out) {
    int m = blockIdx.x * 256 + threadIdx.x;
    float mx = -3.4e38f;
#pragma unroll
    for (int c = 0; c < 16; ++c)
        mx = fmaxf(mx, partial[(size_t)c * M_DIM + m]);
    out[m] = mx;
}

extern "C" void kernel_launch(void* const* d_in, const int* in_sizes, int n_in,
                              void* d_out, int out_size, void* d_ws, size_t ws_size,
                              hipStream_t stream) {
    const float* x = (const float*)d_in[0];
    const float* W = (const float*)d_in[1];
    const float* bias = (const float*)d_in[2];
    float* out = (float*)d_out;

    unsigned short* wp = (unsigned short*)d_ws;                         // 2 MB
    float* bp = (float*)((char*)d_ws + 2 * 1024 * 1024);                // 4 KB
    float* partial = (float*)((char*)d_ws + 2 * 1024 * 1024 + 4096);    // 2 MB

    prep_kernel<<<N_POOL, 256, 0, stream>>>(W, bias, wp, bp);
    gemm_kernel<<<(M_DIM / BM) * (N_POOL / BN), 512, 0, stream>>>(x, wp, bp, partial);
    reduce_kernel<<<M_DIM / 256, 256, 0, stream>>>(partial, out);
}